// Round 15
// baseline (364.783 us; speedup 1.0000x reference)
//
#include <hip/hip_runtime.h>
#include <cstdint>
#include <cstddef>

#define NB 256
#define NS 2500
#define NJ 24
#define DF 131

#define QSEG 4           // n segments (k2m md interface == kMM split-K segs)
#define TSEG 640         // tile-partition segment size: 10 chunks of 64

#define KP 2528          // padded K (c/n) for MFMA A-operands
#define XROWS 2528       // Xn rows (2500 real + 28 zero)
#define LPq 136          // padded l (4 K-steps of 32 + predicated 8-elem tail)
#define CSP 66           // LDS c-stride in shorts (33 dw, odd -> b32 reads clean)
#define OSTRIDE ((size_t)NB * NJ * DF)   // 804864 (partial-segment stride)

using short8 = __attribute__((ext_vector_type(8))) short;
using f32x4  = __attribute__((ext_vector_type(4))) float;

// ---- FULL-path ws byte offsets ----
#define F_XN   0ull                        // [NB][XROWS][LPq] bf16 = 176,029,696
#define F_W1B  176029696ull                // [32][KP] bf16
#define F_QBF  176191488ull                // [NB][32][LPq] bf16
#define F_PO   178419712ull                // [4][NB][NJ][DF] f32 = 12,877,824
#define F_MD   191297536ull                // [NB][QSEG][48] f32
#define F_CS   191494144ull                // [NB*NJ][4] f32
#define F_P    191592448ull                // [NB][NJ][KP] bf16
#define WS_FULL 222656512ull

__device__ __forceinline__ unsigned short f2bf(float x) {
  union { float f; unsigned u; } v; v.f = x;
  unsigned r = v.u + 0x7fffu + ((v.u >> 16) & 1u);   // RNE
  return (unsigned short)(r >> 16);
}
__device__ __forceinline__ float bf2f(unsigned us) {
  union { unsigned u; float f; } v; v.u = us << 16;
  return v.f;
}
__device__ __forceinline__ f32x4 mfma16(short8 a, short8 b, f32x4 c) {
  return __builtin_amdgcn_mfma_f32_16x16x32_bf16(a, b, c, 0, 0, 0);
}

// W1 [24][2500] f32 -> W1b [32][KP] bf16, zero-padded
__global__ __launch_bounds__(256) void kT2(const float* __restrict__ W1,
                                           unsigned short* __restrict__ W1b) {
  int dwi = blockIdx.x * 256 + threadIdx.x;
  if (dwi >= 32 * (KP / 2)) return;
  int row = dwi / (KP / 2);
  int kk = (dwi - row * (KP / 2)) * 2;
  unsigned lo = (row < NJ && kk     < NS) ? f2bf(W1[row * NS + kk])     : 0;
  unsigned hi = (row < NJ && kk + 1 < NS) ? f2bf(W1[row * NS + kk + 1]) : 0;
  ((unsigned*)W1b)[dwi] = lo | (hi << 16);
}

// Fused h-pass + X convert: reads f32 X directly (lane owns l=2lane,2lane+1),
// converts to bf16 in-register, writes Xn AND stages transposed LDS for MFMA.
// Cp[(s*NB+b)][j][l] = sum_{c in kseg s} W1[j][c] X_b[c][l]; also emits
// Xn[b][c][LPq] (rows>=NS and l-pad zeroed).
__global__ __launch_bounds__(512) void kMH(const float* __restrict__ sf,
                                           const unsigned short* __restrict__ W1b,
                                           unsigned short* __restrict__ Xn,
                                           float* __restrict__ Cp) {
  __shared__ unsigned short xs[144 * CSP];        // 19,008 B
  unsigned* xs4 = (unsigned*)xs;
  int b = blockIdx.x >> 2;
  int s = blockIdx.x & 3;
  int w = threadIdx.x >> 6, lane = threadIdx.x & 63;
  int lr = lane & 15, lg = lane >> 4;
  const float* xb = sf + (size_t)b * (NS * DF);
  unsigned* xnb4 = (unsigned*)(Xn + (size_t)b * ((size_t)XROWS * LPq));

  int nu = (w < 2) ? 3 : 2;                       // units u = w, w+8, w+16(<18)
  f32x4 acc[3];
#pragma unroll
  for (int t = 0; t < 3; ++t) acc[t] = (f32x4){0.f, 0.f, 0.f, 0.f};

  int ch0 = s * 10;
  int q = lane & 3;
  unsigned pre[9];
  // prefetch chunk ch0: f32 read + convert
#pragma unroll
  for (int k = 0; k < 8; ++k) {
    int c = ch0 * 64 + w * 8 + k;
    bool vc = c < NS;
    float f0 = vc ? xb[(size_t)c * DF + 2 * lane] : 0.f;
    float f1 = vc ? xb[(size_t)c * DF + 2 * lane + 1] : 0.f;
    pre[k] = (unsigned)f2bf(f0) | ((unsigned)f2bf(f1) << 16);
  }
  pre[8] = 0;
  if (lane < 32) {
    int c = ch0 * 64 + w * 8 + (lane >> 2);
    bool vc = c < NS;
    int l0 = 128 + 2 * q;
    float f0 = (vc && q < 2) ? xb[(size_t)c * DF + l0] : 0.f;      // 128 / 130
    float f1 = (vc && q == 0) ? xb[(size_t)c * DF + 129] : 0.f;
    pre[8] = (unsigned)f2bf(f0) | ((unsigned)f2bf(f1) << 16);
  }

  for (int i = 0; i < 10; ++i) {
    int ch = ch0 + i;
    int c0 = ch * 64;
    int CS = (ch < 39) ? 64 : 32;
    __syncthreads();                               // prev chunk's LDS reads done
    // pre -> Xn (coalesced dword stores) and -> transposed LDS
#pragma unroll
    for (int k = 0; k < 8; ++k) {
      int r = w * 8 + k;
      if (r < CS) {
        xnb4[(size_t)(c0 + r) * (LPq / 2) + lane] = pre[k];
        xs[(2 * lane) * CSP + r]     = (unsigned short)(pre[k] & 0xffffu);
        xs[(2 * lane + 1) * CSP + r] = (unsigned short)(pre[k] >> 16);
      }
    }
    if (lane < 32) {
      int r = w * 8 + (lane >> 2);
      if (r < CS) {
        xnb4[(size_t)(c0 + r) * (LPq / 2) + 64 + q] = pre[8];
        int l0 = 128 + 2 * q;
        xs[l0 * CSP + r]       = (unsigned short)(pre[8] & 0xffffu);
        xs[(l0 + 1) * CSP + r] = (unsigned short)(pre[8] >> 16);
      }
    }
    __syncthreads();
    if (i + 1 < 10) {                              // prefetch next (overlaps MFMA)
      int c1 = c0 + 64;
      int CSn = (ch + 1 < 39) ? 64 : 32;
#pragma unroll
      for (int k = 0; k < 8; ++k) {
        int r = w * 8 + k;
        int c = c1 + r;
        bool vc = (r < CSn) && (c < NS);
        float f0 = vc ? xb[(size_t)c * DF + 2 * lane] : 0.f;
        float f1 = vc ? xb[(size_t)c * DF + 2 * lane + 1] : 0.f;
        pre[k] = (r < CSn) ? ((unsigned)f2bf(f0) | ((unsigned)f2bf(f1) << 16)) : 0u;
      }
      pre[8] = 0;
      if (lane < 32) {
        int r = w * 8 + (lane >> 2);
        int c = c1 + r;
        bool vc = (r < CSn) && (c < NS);
        float f0 = (vc && q < 2) ? xb[(size_t)c * DF + 128 + 2 * q] : 0.f;
        float f1 = (vc && q == 0) ? xb[(size_t)c * DF + 129] : 0.f;
        pre[8] = (unsigned)f2bf(f0) | ((unsigned)f2bf(f1) << 16);
      }
    }
    int nks = CS >> 5;
    for (int ks = 0; ks < nks; ++ks) {
#pragma unroll
      for (int t = 0; t < 3; ++t) {
        if (t < nu) {
          int u = w + 8 * t;
          int m = u / 9, nt = u - 9 * m;
          int arow = m * 16 + lr; if (arow > 31) arow = 31;
          const unsigned short* ap = W1b + (size_t)arow * KP + c0 + ks * 32 + lg * 8;
          short8 av = *(const short8*)ap;
          int bb = (nt * 16 + lr) * (CSP / 2) + ks * 16 + lg * 4;
          unsigned b0 = xs4[bb], b1 = xs4[bb + 1], b2 = xs4[bb + 2], b3 = xs4[bb + 3];
          short8 bv;
          ((unsigned*)&bv)[0] = b0; ((unsigned*)&bv)[1] = b1;
          ((unsigned*)&bv)[2] = b2; ((unsigned*)&bv)[3] = b3;
          acc[t] = mfma16(av, bv, acc[t]);
        }
      }
    }
  }
  float* Cb = Cp + (size_t)(s * NB + b) * (NJ * DF);
#pragma unroll
  for (int t = 0; t < 3; ++t) {
    if (t < nu) {
      int u = w + 8 * t;
      int m = u / 9, nt = u - 9 * m;
      int lcol = nt * 16 + lr;
      if (lcol < DF) {
#pragma unroll
        for (int r = 0; r < 4; ++r) {
          int j = m * 16 + lg * 4 + r;
          if (j < NJ) Cb[(size_t)j * DF + lcol] = acc[t][r];
        }
      }
    }
  }
}

// Split-K out-GEMM vs Xn (round-14 proven body): Cp[(s*NB+b)][j][l] =
// sum_{k in kseg s} A_b[j][k] X_b[k][l]. A = raw P (zero n-pad), astride=NJ.
__global__ __launch_bounds__(512) void kMM(const unsigned short* __restrict__ Xn,
                                           const unsigned short* __restrict__ A,
                                           int astride, int amax,
                                           float* __restrict__ Cp) {
  __shared__ unsigned short xs[144 * CSP];
  unsigned* xs4 = (unsigned*)xs;
  int b = blockIdx.x >> 2;
  int s = blockIdx.x & 3;
  int w = threadIdx.x >> 6, lane = threadIdx.x & 63;
  int lr = lane & 15, lg = lane >> 4;
  const unsigned* xb4 = (const unsigned*)(Xn + (size_t)b * ((size_t)XROWS * LPq));
  const unsigned short* Ab = A + (size_t)b * astride * KP;

  int nu = (w < 2) ? 3 : 2;
  f32x4 acc[3];
#pragma unroll
  for (int t = 0; t < 3; ++t) acc[t] = (f32x4){0.f, 0.f, 0.f, 0.f};

  int ch0 = s * 10;
  unsigned pre[9];
#pragma unroll
  for (int k = 0; k < 8; ++k)
    pre[k] = xb4[(size_t)(ch0 * 64 + w * 8 + k) * (LPq / 2) + lane];
  pre[8] = 0;
  if (lane < 32)
    pre[8] = xb4[(size_t)(ch0 * 64 + w * 8 + (lane >> 2)) * (LPq / 2) + 64 + (lane & 3)];

  for (int i = 0; i < 10; ++i) {
    int ch = ch0 + i;
    int c0 = ch * 64;
    int CS = (ch < 39) ? 64 : 32;
    __syncthreads();
#pragma unroll
    for (int k = 0; k < 8; ++k) {
      int r = w * 8 + k;
      if (r < CS) {
        xs[(2 * lane) * CSP + r]     = (unsigned short)(pre[k] & 0xffffu);
        xs[(2 * lane + 1) * CSP + r] = (unsigned short)(pre[k] >> 16);
      }
    }
    if (lane < 32) {
      int r = w * 8 + (lane >> 2);
      if (r < CS) {
        int l0 = 128 + 2 * (lane & 3);
        xs[l0 * CSP + r]       = (unsigned short)(pre[8] & 0xffffu);
        xs[(l0 + 1) * CSP + r] = (unsigned short)(pre[8] >> 16);
      }
    }
    __syncthreads();
    if (i + 1 < 10) {
      int c1 = c0 + 64;
      int CSn = (ch + 1 < 39) ? 64 : 32;
#pragma unroll
      for (int k = 0; k < 8; ++k) {
        int r = w * 8 + k;
        pre[k] = (r < CSn) ? xb4[(size_t)(c1 + r) * (LPq / 2) + lane] : 0u;
      }
      pre[8] = 0;
      if (lane < 32) {
        int r = w * 8 + (lane >> 2);
        if (r < CSn)
          pre[8] = xb4[(size_t)(c1 + r) * (LPq / 2) + 64 + (lane & 3)];
      }
    }
    int nks = CS >> 5;
    for (int ks = 0; ks < nks; ++ks) {
#pragma unroll
      for (int t = 0; t < 3; ++t) {
        if (t < nu) {
          int u = w + 8 * t;
          int m = u / 9, nt = u - 9 * m;
          int arow = m * 16 + lr; if (arow > amax) arow = amax;
          const unsigned short* ap = Ab + (size_t)arow * KP + c0 + ks * 32 + lg * 8;
          short8 av = *(const short8*)ap;
          int bb = (nt * 16 + lr) * (CSP / 2) + ks * 16 + lg * 4;
          unsigned b0 = xs4[bb], b1 = xs4[bb + 1], b2 = xs4[bb + 2], b3 = xs4[bb + 3];
          short8 bv;
          ((unsigned*)&bv)[0] = b0; ((unsigned*)&bv)[1] = b1;
          ((unsigned*)&bv)[2] = b2; ((unsigned*)&bv)[3] = b3;
          acc[t] = mfma16(av, bv, acc[t]);
        }
      }
    }
  }
  float* Cb = Cp + (size_t)(s * NB + b) * (NJ * DF);
#pragma unroll
  for (int t = 0; t < 3; ++t) {
    if (t < nu) {
      int u = w + 8 * t;
      int m = u / 9, nt = u - 9 * m;
      int lcol = nt * 16 + lr;
      if (lcol < DF) {
#pragma unroll
        for (int r = 0; r < 4; ++r) {
          int j = m * 16 + lg * 4 + r;
          if (j < NJ) Cb[(size_t)j * DF + lcol] = acc[t][r];
        }
      }
    }
  }
}

// out[i] = sum_s cs[bj][s] * po[s][i]  (split-K segs == softmax segs)
__global__ __launch_bounds__(512) void kR4(const float* __restrict__ po,
                                           const float* __restrict__ csb,
                                           float* __restrict__ out) {
  int i = blockIdx.x * 512 + threadIdx.x;        // grid exact: 1572*512 = 804864
  int bj = i / DF;
  const float* cs = csb + (size_t)bj * 4;
  out[i] = cs[0] * po[i] + cs[1] * po[OSTRIDE + i] +
           cs[2] * po[2 * OSTRIDE + i] + cs[3] * po[3 * OSTRIDE + i];
}

// sum 4 h-partials, relu(+b1) -> q = W2@. + b2 -> qbf bf16 [b][32][LPq]
__global__ __launch_bounds__(512) void k1b(const float* __restrict__ po,
                                           const float* __restrict__ W2,
                                           const float* __restrict__ b1v,
                                           const float* __restrict__ b2v,
                                           unsigned short* __restrict__ qbf) {
  int flat = blockIdx.x * 512 + threadIdx.x;      // NB*LPq = 34816 threads
  if (flat >= NB * LPq) return;
  int l = flat % LPq;
  int b = flat / LPq;
  unsigned short* qp = qbf + (size_t)b * (32 * LPq) + l;
  if (l >= DF) {
#pragma unroll
    for (int j = 0; j < 32; ++j) qp[j * LPq] = 0;
    return;
  }
  const float* p0 = po + (size_t)b * (NJ * DF) + l;
  float hv[NJ];
#pragma unroll
  for (int o = 0; o < NJ; ++o)
    hv[o] = fmaxf(b1v[o] + p0[o * DF] + p0[OSTRIDE + o * DF] +
                  p0[2 * OSTRIDE + o * DF] + p0[3 * OSTRIDE + o * DF], 0.f);
  float q[NJ];
  for (int o = 0; o < NJ; ++o) {
    float sv = b2v[o];
#pragma unroll
    for (int i = 0; i < NJ; ++i) sv = fmaf(W2[o * NJ + i], hv[i], sv);
    q[o] = sv;
  }
#pragma unroll
  for (int j = 0; j < NJ; ++j) qp[j * LPq] = f2bf(q[j]);
#pragma unroll
  for (int j = NJ; j < 32; ++j) qp[j * LPq] = 0;
}

// MFMA scores from Xn: P = exp(S - m_seg) bf16 + per-seg (m,d). seg = n/640.
__global__ __launch_bounds__(512) void k2m(const unsigned short* __restrict__ Xn,
                                           const unsigned short* __restrict__ qbf,
                                           unsigned short* __restrict__ P,
                                           float* __restrict__ md) {
  __shared__ float wm[8][24];
  __shared__ float wd[8][24];
  int b = blockIdx.x >> 2, seg = blockIdx.x & 3;
  int w = threadIdx.x >> 6, lane = threadIdx.x & 63;
  int lr = lane & 15, lg = lane >> 4;
  const short8 z8 = {0, 0, 0, 0, 0, 0, 0, 0};

  const unsigned short* qb = qbf + (size_t)b * (32 * LPq);
  short8 aq0[5], aq1[5];
#pragma unroll
  for (int ks = 0; ks < 4; ++ks) {
    aq0[ks] = *(const short8*)(qb + (size_t)lr * LPq + ks * 32 + lg * 8);
    aq1[ks] = *(const short8*)(qb + (size_t)(16 + lr) * LPq + ks * 32 + lg * 8);
  }
  aq0[4] = (lg == 0) ? *(const short8*)(qb + (size_t)lr * LPq + 128) : z8;
  aq1[4] = (lg == 0) ? *(const short8*)(qb + (size_t)(16 + lr) * LPq + 128) : z8;

  const unsigned short* xb = Xn + (size_t)b * ((size_t)XROWS * LPq);
  int ntl = (seg < 3) ? 40 : 37;

  f32x4 s0[5], s1[5];
  float m8[8];
#pragma unroll
  for (int r = 0; r < 8; ++r) m8[r] = -1e30f;

#pragma unroll
  for (int i = 0; i < 5; ++i) {
    s0[i] = (f32x4){0.f, 0.f, 0.f, 0.f};
    s1[i] = (f32x4){0.f, 0.f, 0.f, 0.f};
    int ti = w + 8 * i;
    if (ti < ntl) {
      int n = (seg * 40 + ti) * 16 + lr;
      const unsigned short* bp = xb + (size_t)n * LPq + lg * 8;
      short8 bx[5];
#pragma unroll
      for (int ks = 0; ks < 4; ++ks) bx[ks] = *(const short8*)(bp + ks * 32);
      bx[4] = (lg == 0) ? *(const short8*)(xb + (size_t)n * LPq + 128) : z8;
      f32x4 a0 = {0.f, 0.f, 0.f, 0.f}, a1 = {0.f, 0.f, 0.f, 0.f};
#pragma unroll
      for (int ks = 0; ks < 5; ++ks) {
        a0 = mfma16(aq0[ks], bx[ks], a0);
        a1 = mfma16(aq1[ks], bx[ks], a1);
      }
      s0[i] = a0; s1[i] = a1;
#pragma unroll
      for (int r = 0; r < 4; ++r) {
        m8[r]     = fmaxf(m8[r],     a0[r]);
        m8[4 + r] = fmaxf(m8[4 + r], a1[r]);
      }
    }
  }
#pragma unroll
  for (int r = 0; r < 8; ++r)
#pragma unroll
    for (int off = 1; off < 16; off <<= 1)
      m8[r] = fmaxf(m8[r], __shfl_xor(m8[r], off));
  if (lr == 0) {
#pragma unroll
    for (int r = 0; r < 4; ++r) {
      wm[w][lg * 4 + r] = m8[r];
      if (lg < 2) wm[w][16 + lg * 4 + r] = m8[4 + r];
    }
  }
  __syncthreads();
  float mseg[8];
#pragma unroll
  for (int r = 0; r < 4; ++r) {
    float m0 = wm[0][lg * 4 + r];
#pragma unroll
    for (int wv = 1; wv < 8; ++wv) m0 = fmaxf(m0, wm[wv][lg * 4 + r]);
    mseg[r] = m0;
    int j1 = 16 + (lg & 1) * 4 + r;
    float m1 = wm[0][j1];
#pragma unroll
    for (int wv = 1; wv < 8; ++wv) m1 = fmaxf(m1, wm[wv][j1]);
    mseg[4 + r] = m1;
  }
  float d8[8];
#pragma unroll
  for (int r = 0; r < 8; ++r) d8[r] = 0.f;
#pragma unroll
  for (int i = 0; i < 5; ++i) {
    int ti = w + 8 * i;
    if (ti < ntl) {
      int n = (seg * 40 + ti) * 16 + lr;
      bool valid = n < NS;
#pragma unroll
      for (int r = 0; r < 4; ++r) {
        float p0 = __expf(s0[i][r] - mseg[r]);
        float p1 = __expf(s1[i][r] - mseg[4 + r]);
        if (valid) {
          P[((size_t)b * NJ + lg * 4 + r) * KP + n] = f2bf(p0);
          d8[r] += p0;
          if (lg < 2) {
            P[((size_t)b * NJ + 16 + lg * 4 + r) * KP + n] = f2bf(p1);
            d8[4 + r] += p1;
          }
        }
      }
    }
  }
#pragma unroll
  for (int r = 0; r < 8; ++r)
#pragma unroll
    for (int off = 1; off < 16; off <<= 1)
      d8[r] += __shfl_xor(d8[r], off);
  if (lr == 0) {
#pragma unroll
    for (int r = 0; r < 4; ++r) {
      wd[w][lg * 4 + r] = d8[r];
      if (lg < 2) wd[w][16 + lg * 4 + r] = d8[4 + r];
    }
  }
  __syncthreads();
  if (threadIdx.x < NJ) {
    int j = threadIdx.x;
    float m = wm[0][j], d = 0.f;
#pragma unroll
    for (int wv = 1; wv < 8; ++wv) m = fmaxf(m, wm[wv][j]);
#pragma unroll
    for (int wv = 0; wv < 8; ++wv) d += wd[wv][j];
    float* mp = md + ((size_t)b * QSEG + seg) * 48;
    mp[j] = m;
    mp[24 + j] = d;
  }
}

// combine md -> cs[4]; write attention f32 from RAW P; zero P's n-pad;
// store cs for kR4. P is NOT renormalized (factored into kR4).
__global__ __launch_bounds__(256) void kW(unsigned short* __restrict__ P,
                                          const float* __restrict__ md,
                                          float* __restrict__ attn,
                                          float* __restrict__ csb) {
  int bj = blockIdx.x;
  int b = bj / NJ, j = bj - b * NJ;
  const float* mp = md + (size_t)b * (QSEG * 48);
  float ms[QSEG];
  float m = -1e30f;
#pragma unroll
  for (int s = 0; s < QSEG; ++s) { ms[s] = mp[s * 48 + j]; m = fmaxf(m, ms[s]); }
  float d = 0.f;
#pragma unroll
  for (int s = 0; s < QSEG; ++s) d += mp[s * 48 + 24 + j] * __expf(ms[s] - m);
  float rinv = 1.f / d;
  float cs[QSEG];
#pragma unroll
  for (int s = 0; s < QSEG; ++s) cs[s] = __expf(ms[s] - m) * rinv;
  if (threadIdx.x < QSEG) {
    float v = cs[0];
    if (threadIdx.x == 1) v = cs[1];
    if (threadIdx.x == 2) v = cs[2];
    if (threadIdx.x == 3) v = cs[3];
    csb[(size_t)bj * QSEG + threadIdx.x] = v;
  }

  unsigned* prow = (unsigned*)(P + (size_t)bj * KP);
  float2* arow = (float2*)(attn + (size_t)bj * NS);
  for (int i = threadIdx.x; i < NS / 2; i += 256) {
    unsigned pk = prow[i];
    int n0 = 2 * i;
    float p0 = bf2f(pk & 0xffffu) * cs[n0 / TSEG];
    float p1 = bf2f(pk >> 16) * cs[(n0 + 1) / TSEG];
    arow[i] = make_float2(p0, p1);
  }
  if (threadIdx.x < (KP - NS) / 2) prow[NS / 2 + threadIdx.x] = 0;   // pad zeros
}

// =============== FP32 fallback (round-3, known-pass) ===============
#define KSEG 8
#define CSEG 313
#define SEGN 625
#define TN 64
#define LDP 132
#define WS_W1T 0u
#define WS_QTF 60000u
#define WS_MDF (WS_QTF + 804864u)
#define WS_PHF (WS_MDF + (unsigned)(NB * QSEG * 48))
#define SEGSTRIDE ((size_t)NB * NJ * DF)

__global__ __launch_bounds__(256) void kT_f(const float* __restrict__ W1,
                                            float* __restrict__ W1t) {
  int i = blockIdx.x * 256 + threadIdx.x;
  if (i >= NJ * NS) return;
  int o = i / NS, c = i - o * NS;
  W1t[c * NJ + o] = W1[i];
}

__global__ __launch_bounds__(192) void kH_f(const float* __restrict__ sf,
                                            const float* __restrict__ W1t,
                                            float* __restrict__ ph) {
  int b = blockIdx.x >> 3;
  int s = blockIdx.x & 7;
  int l = threadIdx.x;
  int c0 = s * CSEG;
  int cnt = NS - c0; if (cnt > CSEG) cnt = CSEG;
  const float* xp = sf + (size_t)b * (NS * DF) + (size_t)c0 * DF;
  const float* wp = W1t + (size_t)c0 * NJ;
  float acc[NJ];
#pragma unroll
  for (int o = 0; o < NJ; ++o) acc[o] = 0.f;
  if (l < DF) {
#pragma unroll 2
    for (int c = 0; c < cnt; ++c) {
      float xv = xp[(size_t)c * DF + l];
#pragma unroll
      for (int o = 0; o < NJ; ++o) acc[o] = fmaf(wp[c * NJ + o], xv, acc[o]);
    }
    float* pp = ph + (size_t)(s * NB + b) * (NJ * DF) + l;
#pragma unroll
    for (int o = 0; o < NJ; ++o) pp[o * DF] = acc[o];
  }
}

__global__ __launch_bounds__(512) void k1b_f(const float* __restrict__ ph,
                                             const float* __restrict__ W2,
                                             const float* __restrict__ b1v,
                                             const float* __restrict__ b2v,
                                             float* __restrict__ q_t) {
  int flat = blockIdx.x * 512 + threadIdx.x;
  if (flat >= NB * DF) return;
  int l = flat % DF;
  int b = flat / DF;
  const float* p0 = ph + (size_t)(b * NJ) * DF + l;
  float hv[NJ];
#pragma unroll
  for (int o = 0; o < NJ; ++o) hv[o] = b1v[o];
  for (int s = 0; s < KSEG; ++s) {
#pragma unroll
    for (int o = 0; o < NJ; ++o) hv[o] += p0[s * SEGSTRIDE + o * DF];
  }
#pragma unroll
  for (int o = 0; o < NJ; ++o) hv[o] = fmaxf(hv[o], 0.f);
  float q[NJ];
  for (int o = 0; o < NJ; ++o) {
    float sv = b2v[o];
#pragma unroll
    for (int i = 0; i < NJ; ++i) sv = fmaf(W2[o * NJ + i], hv[i], sv);
    q[o] = sv;
  }
  float4* qp = (float4*)(q_t + (size_t)flat * NJ);
#pragma unroll
  for (int v = 0; v < 6; ++v)
    qp[v] = make_float4(q[4 * v], q[4 * v + 1], q[4 * v + 2], q[4 * v + 3]);
}

__global__ __launch_bounds__(256) void k2_f(const float* __restrict__ sf,
                                            const float* __restrict__ q_t,
                                            float* __restrict__ raw,
                                            float* __restrict__ md) {
  __shared__ __align__(16) float xs[TN * LDP];
  int b = blockIdx.x >> 2;
  int s = blockIdx.x & 3;
  int tid = threadIdx.x;
  int wid = tid >> 6, lane = tid & 63;
  int jq = __builtin_amdgcn_readfirstlane(wid);

  const float* sft = sf + (size_t)b * (NS * DF) + (size_t)(s * SEGN) * DF;
  const float* qb = q_t + (size_t)b * (DF * NJ) + jq * 6;
  float* rawb = raw + (size_t)b * (NJ * NS) + (size_t)(s * SEGN);

  float m6[6], d6[6];
#pragma unroll
  for (int i = 0; i < 6; ++i) { m6[i] = -1e30f; d6[i] = 0.f; }

  const int NT = (SEGN + TN - 1) / TN;
  for (int t = 0; t < NT; ++t) {
    int n0 = t * TN;
    int nmax = SEGN - n0; if (nmax > TN) nmax = TN;
    __syncthreads();
#pragma unroll
    for (int rr = 0; rr < 16; ++rr) {
      int r = wid * 16 + rr;
      if (r < nmax) {
        const float* g = sft + (size_t)(n0 + r) * DF;
        float* d = xs + r * LDP;
        d[lane] = g[lane];
        d[64 + lane] = g[64 + lane];
        if (lane < 3) d[128 + lane] = g[128 + lane];
      }
    }
    __syncthreads();
    if (lane < nmax) {
      const float* xrow = xs + lane * LDP;
      float sa[6];
#pragma unroll
      for (int i = 0; i < 6; ++i) sa[i] = 0.f;
      for (int l4 = 0; l4 < 32; ++l4) {
        float4 xv = *(const float4*)(xrow + 4 * l4);
        const float* q4 = qb + (4 * l4) * NJ;
#pragma unroll
        for (int i = 0; i < 6; ++i) sa[i] = fmaf(q4[i], xv.x, sa[i]);
#pragma unroll
        for (int i = 0; i < 6; ++i) sa[i] = fmaf(q4[NJ + i], xv.y, sa[i]);
#pragma unroll
        for (int i = 0; i < 6; ++i) sa[i] = fmaf(q4[2 * NJ + i], xv.z, sa[i]);
#pragma unroll
        for (int i = 0; i < 6; ++i) sa[i] = fmaf(q4[3 * NJ + i], xv.w, sa[i]);
      }
#pragma unroll
      for (int l = 128; l < DF; ++l) {
        float xv = xrow[l];
#pragma unroll
        for (int i = 0; i < 6; ++i) sa[i] = fmaf(qb[l * NJ + i], xv, sa[i]);
      }
      int nr = n0 + lane;
#pragma unroll
      for (int i = 0; i < 6; ++i) {
        rawb[(size_t)(jq * 6 + i) * NS + nr] = sa[i];
        float mn = fmaxf(m6[i], sa[i]);
        d6[i] = d6[i] * __expf(m6[i] - mn) + __expf(sa[i] - mn);
        m6[i] = mn;
      }
    }
  }
#pragma unroll
  for (int i = 0; i < 6; ++i) {
    float m = m6[i], d = d6[i];
    for (int off = 32; off > 0; off >>= 1) {
      float mo = __shfl_xor(m, off);
      float dd = __shfl_xor(d, off);
      float nm = fmaxf(m, mo);
      d = d * __expf(m - nm) + dd * __expf(mo - nm);
      m = nm;
    }
    m6[i] = m; d6[i] = d;
  }
  if (lane == 0) {
    float* mp = md + ((size_t)b * QSEG + s) * 48;
#pragma unroll
    for (int i = 0; i < 6; ++i) {
      mp[jq * 6 + i] = m6[i];
      mp[24 + jq * 6 + i] = d6[i];
    }
  }
}

__global__ __launch_bounds__(256) void k3_f(float* __restrict__ attn,
                                            const float* __restrict__ md) {
  int bj = blockIdx.x;
  int b = bj / NJ;
  int j = bj - b * NJ;
  const float* mp = md + (size_t)b * (QSEG * 48);
  float m = -1e30f, d = 0.f;
#pragma unroll
  for (int s = 0; s < QSEG; ++s) {
    float ms = mp[s * 48 + j], ds = mp[s * 48 + 24 + j];
    float nm = fmaxf(m, ms);
    d = d * __expf(m - nm) + ds * __expf(ms - nm);
    m = nm;
  }
  float r = 1.f / d;
  float* p = attn + (size_t)bj * NS;
  for (int n = threadIdx.x; n < NS; n += 256)
    p[n] = __expf(p[n] - m) * r;
}

__global__ __launch_bounds__(192) void k4_f(const float* __restrict__ sf,
                                            const float* __restrict__ attn,
                                            float* __restrict__ po) {
  int b = blockIdx.x >> 3;
  int s = blockIdx.x & 7;
  int l = threadIdx.x;
  int n0 = s * CSEG;
  int cnt = NS - n0; if (cnt > CSEG) cnt = CSEG;
  const float* xp = sf + (size_t)b * (NS * DF) + (size_t)n0 * DF;
  const float* ap = attn + (size_t)b * (NJ * NS) + n0;
  float acc[NJ];
#pragma unroll
  for (int o = 0; o < NJ; ++o) acc[o] = 0.f;
  if (l < DF) {
#pragma unroll 2
    for (int n = 0; n < cnt; ++n) {
      float xv = xp[(size_t)n * DF + l];
#pragma unroll
      for (int o = 0; o < NJ; ++o) acc[o] = fmaf(ap[(size_t)o * NS + n], xv, acc[o]);
    }
    float* pp = po + (size_t)(s * NB + b) * (NJ * DF) + l;
#pragma unroll
    for (int o = 0; o < NJ; ++o) pp[o * DF] = acc[o];
  }
}

__global__ __launch_bounds__(512) void k5_f(const float* __restrict__ po,
                                            float* __restrict__ out) {
  int i = blockIdx.x * 512 + threadIdx.x;
  float v = 0.f;
#pragma unroll
  for (int s = 0; s < KSEG; ++s) v += po[s * SEGSTRIDE + i];
  out[i] = v;
}

extern "C" void kernel_launch(void* const* d_in, const int* in_sizes, int n_in,
                              void* d_out, int out_size, void* d_ws, size_t ws_size,
                              hipStream_t stream) {
  const float* sf = (const float*)d_in[0];
  const float* W1 = (const float*)d_in[1];
  const float* b1 = (const float*)d_in[2];
  const float* W2 = (const float*)d_in[3];
  const float* b2 = (const float*)d_in[4];
  float* out = (float*)d_out;
  float* attn = out + (size_t)NB * NJ * DF;

  if (ws_size >= WS_FULL) {
    unsigned short* Xn  = (unsigned short*)((char*)d_ws + F_XN);
    unsigned short* W1b = (unsigned short*)((char*)d_ws + F_W1B);
    unsigned short* qbf = (unsigned short*)((char*)d_ws + F_QBF);
    float* po   = (float*)((char*)d_ws + F_PO);
    float* md   = (float*)((char*)d_ws + F_MD);
    float* csb  = (float*)((char*)d_ws + F_CS);
    unsigned short* P   = (unsigned short*)((char*)d_ws + F_P);

    kT2<<<158, 256, 0, stream>>>(W1, W1b);
    kMH<<<NB * 4, 512, 0, stream>>>(sf, W1b, Xn, po);      // h partials + Xn
    k1b<<<68, 512, 0, stream>>>(po, W2, b1, b2, qbf);      // reduce + q
    k2m<<<NB * QSEG, 512, 0, stream>>>(Xn, qbf, P, md);
    kW <<<NB * NJ, 256, 0, stream>>>(P, md, attn, csb);
    kMM<<<NB * 4, 512, 0, stream>>>(Xn, P, NJ, 23, po);    // out partials (raw P)
    kR4<<<1572, 512, 0, stream>>>(po, csb, out);
  } else {
    float* ws = (float*)d_ws;
    float* W1t = ws + WS_W1T;
    float* q_t = ws + WS_QTF;
    float* md  = ws + WS_MDF;
    float* ph  = ws + WS_PHF;
    kT_f <<<235, 256, 0, stream>>>(W1, W1t);
    kH_f <<<NB * KSEG, 192, 0, stream>>>(sf, W1t, ph);
    k1b_f<<<66, 512, 0, stream>>>(ph, W2, b1, b2, q_t);
    k2_f <<<NB * QSEG, 256, 0, stream>>>(sf, q_t, attn, md);
    k3_f <<<NB * NJ, 256, 0, stream>>>(attn, md);
    k4_f <<<NB * KSEG, 192, 0, stream>>>(sf, attn, ph);
    k5_f <<<1572, 512, 0, stream>>>(ph, out);
  }
}

// Round 16
// 318.848 us; speedup vs baseline: 1.1441x; 1.1441x over previous
//
#include <hip/hip_runtime.h>
#include <cstdint>
#include <cstddef>

#define NB 256
#define NS 2500
#define NJ 24
#define DF 131

#define QSEG 4           // n segments (k2m md interface == kMM split-K segs)
#define TSEG 640         // tile-partition segment size: 10 chunks of 64

#define KP 2528          // padded K (c/n) for MFMA A-operands
#define XROWS 2528       // Xn rows (2500 real + 28 zero)
#define LPq 136          // padded l (4 K-steps of 32 + predicated 8-elem tail)
#define CSP 66           // LDS c-stride in shorts (33 dw, odd -> b32 reads clean)
#define OSTRIDE ((size_t)NB * NJ * DF)   // 804864 (partial-segment stride)

using short8 = __attribute__((ext_vector_type(8))) short;
using f32x4  = __attribute__((ext_vector_type(4))) float;

// ---- FULL-path ws byte offsets ----
#define F_XN   0ull                        // [NB][XROWS][LPq] bf16 = 176,029,696
#define F_W1B  176029696ull                // [32][KP] bf16
#define F_QBF  176191488ull                // [NB][32][LPq] bf16
#define F_PO   178419712ull                // [4][NB][NJ][DF] f32 = 12,877,824
#define F_MD   191297536ull                // [NB][QSEG][48] f32
#define F_CS   191494144ull                // [NB*NJ][4] f32
#define F_P    191592448ull                // [NB][NJ][KP] bf16
#define WS_FULL 222656512ull

__device__ __forceinline__ unsigned short f2bf(float x) {
  union { float f; unsigned u; } v; v.f = x;
  unsigned r = v.u + 0x7fffu + ((v.u >> 16) & 1u);   // RNE
  return (unsigned short)(r >> 16);
}
__device__ __forceinline__ float bf2f(unsigned us) {
  union { unsigned u; float f; } v; v.u = us << 16;
  return v.f;
}
__device__ __forceinline__ f32x4 mfma16(short8 a, short8 b, f32x4 c) {
  return __builtin_amdgcn_mfma_f32_16x16x32_bf16(a, b, c, 0, 0, 0);
}

// W1 [24][2500] f32 -> W1b [32][KP] bf16, zero-padded
__global__ __launch_bounds__(256) void kT2(const float* __restrict__ W1,
                                           unsigned short* __restrict__ W1b) {
  int dwi = blockIdx.x * 256 + threadIdx.x;
  if (dwi >= 32 * (KP / 2)) return;
  int row = dwi / (KP / 2);
  int kk = (dwi - row * (KP / 2)) * 2;
  unsigned lo = (row < NJ && kk     < NS) ? f2bf(W1[row * NS + kk])     : 0;
  unsigned hi = (row < NJ && kk + 1 < NS) ? f2bf(W1[row * NS + kk + 1]) : 0;
  ((unsigned*)W1b)[dwi] = lo | (hi << 16);
}

// Pure-stream convert: X f32 [b][c][l] -> Xn bf16 [b][c][LPq]  (round-14 proven)
__global__ __launch_bounds__(256) void kPn(const float* __restrict__ sf,
                                           unsigned short* __restrict__ Xn) {
  int b = blockIdx.x / 20;
  int chunk = blockIdx.x - 20 * b;
  int c0 = chunk * 128;
  int w = threadIdx.x >> 6, lane = threadIdx.x & 63;
  const float* xb = sf + (size_t)b * (NS * DF);
  unsigned short* xnb = Xn + (size_t)b * ((size_t)XROWS * LPq);

#pragma unroll 4
  for (int i = 0; i < 32; ++i) {
    int r = w * 32 + i;
    int c = c0 + r;
    if (c >= XROWS) continue;
    bool vc = c < NS;
    const float* g = xb + (size_t)c * DF;
    float v0 = vc ? g[lane] : 0.f;                 // coalesced
    float v1 = vc ? g[64 + lane] : 0.f;
    float v2 = (vc && lane < 3) ? g[128 + lane] : 0.f;
    unsigned short* d = xnb + (size_t)c * LPq;
    d[lane] = f2bf(v0);
    d[64 + lane] = f2bf(v1);
    if (lane < 8) d[128 + lane] = (lane < 3) ? f2bf(v2) : (unsigned short)0;
  }
}

// Split-K small-GEMM vs Xn with DOUBLE-BUFFERED LDS (1 barrier/chunk):
// Cp[(s*NB+b)][j][l] = sum_{k in kseg s} A_b[j][k] X_b[k][l]
// A rows k-contiguous (KP stride), per-batch stride astride, row clamp amax.
__global__ __launch_bounds__(512) void kMM(const unsigned short* __restrict__ Xn,
                                           const unsigned short* __restrict__ A,
                                           int astride, int amax,
                                           float* __restrict__ Cp) {
  __shared__ unsigned short xs[2][144 * CSP];     // 38,016 B
  int b = blockIdx.x >> 2;
  int s = blockIdx.x & 3;
  int w = threadIdx.x >> 6, lane = threadIdx.x & 63;
  int lr = lane & 15, lg = lane >> 4;
  const unsigned* xb4 = (const unsigned*)(Xn + (size_t)b * ((size_t)XROWS * LPq));
  const unsigned short* Ab = A + (size_t)b * astride * KP;

  int nu = (w < 2) ? 3 : 2;                       // units u = w, w+8, w+16(<18)
  f32x4 acc[3];
#pragma unroll
  for (int t = 0; t < 3; ++t) acc[t] = (f32x4){0.f, 0.f, 0.f, 0.f};

  int ch0 = s * 10;
  int q = lane & 3;
  unsigned pre[9];
  // prefetch chunk ch0 (always full 64 rows: ch0 in {0,10,20,30})
#pragma unroll
  for (int k = 0; k < 8; ++k)
    pre[k] = xb4[(size_t)(ch0 * 64 + w * 8 + k) * (LPq / 2) + lane];
  pre[8] = 0;
  if (lane < 32)
    pre[8] = xb4[(size_t)(ch0 * 64 + w * 8 + (lane >> 2)) * (LPq / 2) + 64 + q];
  // stage into buf0
#pragma unroll
  for (int k = 0; k < 8; ++k) {
    int r = w * 8 + k;
    xs[0][(2 * lane) * CSP + r]     = (unsigned short)(pre[k] & 0xffffu);
    xs[0][(2 * lane + 1) * CSP + r] = (unsigned short)(pre[k] >> 16);
  }
  if (lane < 32) {
    int r = w * 8 + (lane >> 2);
    int l0 = 128 + 2 * q;
    xs[0][l0 * CSP + r]       = (unsigned short)(pre[8] & 0xffffu);
    xs[0][(l0 + 1) * CSP + r] = (unsigned short)(pre[8] >> 16);
  }

  for (int i = 0; i < 10; ++i) {
    int ch = ch0 + i;
    int c0 = ch * 64;
    int CS = (ch < 39) ? 64 : 32;
    int cur = i & 1;
    __syncthreads();                               // buf[cur] staged, prev reads done
    int CSn = 0;
    if (i + 1 < 10) {                              // issue next-chunk loads FIRST
      int c1 = c0 + 64;
      CSn = (ch + 1 < 39) ? 64 : 32;
#pragma unroll
      for (int k = 0; k < 8; ++k) {
        int r = w * 8 + k;
        pre[k] = (r < CSn) ? xb4[(size_t)(c1 + r) * (LPq / 2) + lane] : 0u;
      }
      pre[8] = 0;
      if (lane < 32) {
        int r = w * 8 + (lane >> 2);
        if (r < CSn)
          pre[8] = xb4[(size_t)(c1 + r) * (LPq / 2) + 64 + q];
      }
    }
    // MFMA on buf[cur] (overlaps the loads above)
    const unsigned* xc4 = (const unsigned*)xs[cur];
    int nks = CS >> 5;
    for (int ks = 0; ks < nks; ++ks) {
#pragma unroll
      for (int t = 0; t < 3; ++t) {
        if (t < nu) {
          int u = w + 8 * t;
          int m = u / 9, nt = u - 9 * m;
          int arow = m * 16 + lr; if (arow > amax) arow = amax;
          const unsigned short* ap = Ab + (size_t)arow * KP + c0 + ks * 32 + lg * 8;
          short8 av = *(const short8*)ap;
          int bb = (nt * 16 + lr) * (CSP / 2) + ks * 16 + lg * 4;
          unsigned b0 = xc4[bb], b1 = xc4[bb + 1], b2 = xc4[bb + 2], b3 = xc4[bb + 3];
          short8 bv;
          ((unsigned*)&bv)[0] = b0; ((unsigned*)&bv)[1] = b1;
          ((unsigned*)&bv)[2] = b2; ((unsigned*)&bv)[3] = b3;
          acc[t] = mfma16(av, bv, acc[t]);
        }
      }
    }
    // stage next chunk into the other buffer (no barrier needed until next iter)
    if (i + 1 < 10) {
      unsigned short* xn = xs[cur ^ 1];
#pragma unroll
      for (int k = 0; k < 8; ++k) {
        int r = w * 8 + k;
        if (r < CSn) {
          xn[(2 * lane) * CSP + r]     = (unsigned short)(pre[k] & 0xffffu);
          xn[(2 * lane + 1) * CSP + r] = (unsigned short)(pre[k] >> 16);
        }
      }
      if (lane < 32) {
        int r = w * 8 + (lane >> 2);
        if (r < CSn) {
          int l0 = 128 + 2 * q;
          xn[l0 * CSP + r]       = (unsigned short)(pre[8] & 0xffffu);
          xn[(l0 + 1) * CSP + r] = (unsigned short)(pre[8] >> 16);
        }
      }
    }
  }
  float* Cb = Cp + (size_t)(s * NB + b) * (NJ * DF);
#pragma unroll
  for (int t = 0; t < 3; ++t) {
    if (t < nu) {
      int u = w + 8 * t;
      int m = u / 9, nt = u - 9 * m;
      int lcol = nt * 16 + lr;
      if (lcol < DF) {
#pragma unroll
        for (int r = 0; r < 4; ++r) {
          int j = m * 16 + lg * 4 + r;
          if (j < NJ) Cb[(size_t)j * DF + lcol] = acc[t][r];
        }
      }
    }
  }
}

// out[i] = sum_s cs[bj][s] * po[s][i]  (split-K segs == softmax segs)
__global__ __launch_bounds__(512) void kR4(const float* __restrict__ po,
                                           const float* __restrict__ csb,
                                           float* __restrict__ out) {
  int i = blockIdx.x * 512 + threadIdx.x;        // grid exact: 1572*512 = 804864
  int bj = i / DF;
  const float* cs = csb + (size_t)bj * 4;
  out[i] = cs[0] * po[i] + cs[1] * po[OSTRIDE + i] +
           cs[2] * po[2 * OSTRIDE + i] + cs[3] * po[3 * OSTRIDE + i];
}

// sum 4 h-partials, relu(+b1) -> q = W2@. + b2 -> qbf bf16 [b][32][LPq]
__global__ __launch_bounds__(512) void k1b(const float* __restrict__ po,
                                           const float* __restrict__ W2,
                                           const float* __restrict__ b1v,
                                           const float* __restrict__ b2v,
                                           unsigned short* __restrict__ qbf) {
  int flat = blockIdx.x * 512 + threadIdx.x;      // NB*LPq = 34816 threads
  if (flat >= NB * LPq) return;
  int l = flat % LPq;
  int b = flat / LPq;
  unsigned short* qp = qbf + (size_t)b * (32 * LPq) + l;
  if (l >= DF) {
#pragma unroll
    for (int j = 0; j < 32; ++j) qp[j * LPq] = 0;
    return;
  }
  const float* p0 = po + (size_t)b * (NJ * DF) + l;
  float hv[NJ];
#pragma unroll
  for (int o = 0; o < NJ; ++o)
    hv[o] = fmaxf(b1v[o] + p0[o * DF] + p0[OSTRIDE + o * DF] +
                  p0[2 * OSTRIDE + o * DF] + p0[3 * OSTRIDE + o * DF], 0.f);
  float q[NJ];
  for (int o = 0; o < NJ; ++o) {
    float sv = b2v[o];
#pragma unroll
    for (int i = 0; i < NJ; ++i) sv = fmaf(W2[o * NJ + i], hv[i], sv);
    q[o] = sv;
  }
#pragma unroll
  for (int j = 0; j < NJ; ++j) qp[j * LPq] = f2bf(q[j]);
#pragma unroll
  for (int j = NJ; j < 32; ++j) qp[j * LPq] = 0;
}

// MFMA scores from Xn: P = exp(S - m_seg) bf16 + per-seg (m,d). seg = n/640.
__global__ __launch_bounds__(512) void k2m(const unsigned short* __restrict__ Xn,
                                           const unsigned short* __restrict__ qbf,
                                           unsigned short* __restrict__ P,
                                           float* __restrict__ md) {
  __shared__ float wm[8][24];
  __shared__ float wd[8][24];
  int b = blockIdx.x >> 2, seg = blockIdx.x & 3;
  int w = threadIdx.x >> 6, lane = threadIdx.x & 63;
  int lr = lane & 15, lg = lane >> 4;
  const short8 z8 = {0, 0, 0, 0, 0, 0, 0, 0};

  const unsigned short* qb = qbf + (size_t)b * (32 * LPq);
  short8 aq0[5], aq1[5];
#pragma unroll
  for (int ks = 0; ks < 4; ++ks) {
    aq0[ks] = *(const short8*)(qb + (size_t)lr * LPq + ks * 32 + lg * 8);
    aq1[ks] = *(const short8*)(qb + (size_t)(16 + lr) * LPq + ks * 32 + lg * 8);
  }
  aq0[4] = (lg == 0) ? *(const short8*)(qb + (size_t)lr * LPq + 128) : z8;
  aq1[4] = (lg == 0) ? *(const short8*)(qb + (size_t)(16 + lr) * LPq + 128) : z8;

  const unsigned short* xb = Xn + (size_t)b * ((size_t)XROWS * LPq);
  int ntl = (seg < 3) ? 40 : 37;

  f32x4 s0[5], s1[5];
  float m8[8];
#pragma unroll
  for (int r = 0; r < 8; ++r) m8[r] = -1e30f;

#pragma unroll
  for (int i = 0; i < 5; ++i) {
    s0[i] = (f32x4){0.f, 0.f, 0.f, 0.f};
    s1[i] = (f32x4){0.f, 0.f, 0.f, 0.f};
    int ti = w + 8 * i;
    if (ti < ntl) {
      int n = (seg * 40 + ti) * 16 + lr;
      const unsigned short* bp = xb + (size_t)n * LPq + lg * 8;
      short8 bx[5];
#pragma unroll
      for (int ks = 0; ks < 4; ++ks) bx[ks] = *(const short8*)(bp + ks * 32);
      bx[4] = (lg == 0) ? *(const short8*)(xb + (size_t)n * LPq + 128) : z8;
      f32x4 a0 = {0.f, 0.f, 0.f, 0.f}, a1 = {0.f, 0.f, 0.f, 0.f};
#pragma unroll
      for (int ks = 0; ks < 5; ++ks) {
        a0 = mfma16(aq0[ks], bx[ks], a0);
        a1 = mfma16(aq1[ks], bx[ks], a1);
      }
      s0[i] = a0; s1[i] = a1;
#pragma unroll
      for (int r = 0; r < 4; ++r) {
        m8[r]     = fmaxf(m8[r],     a0[r]);
        m8[4 + r] = fmaxf(m8[4 + r], a1[r]);
      }
    }
  }
#pragma unroll
  for (int r = 0; r < 8; ++r)
#pragma unroll
    for (int off = 1; off < 16; off <<= 1)
      m8[r] = fmaxf(m8[r], __shfl_xor(m8[r], off));
  if (lr == 0) {
#pragma unroll
    for (int r = 0; r < 4; ++r) {
      wm[w][lg * 4 + r] = m8[r];
      if (lg < 2) wm[w][16 + lg * 4 + r] = m8[4 + r];
    }
  }
  __syncthreads();
  float mseg[8];
#pragma unroll
  for (int r = 0; r < 4; ++r) {
    float m0 = wm[0][lg * 4 + r];
#pragma unroll
    for (int wv = 1; wv < 8; ++wv) m0 = fmaxf(m0, wm[wv][lg * 4 + r]);
    mseg[r] = m0;
    int j1 = 16 + (lg & 1) * 4 + r;
    float m1 = wm[0][j1];
#pragma unroll
    for (int wv = 1; wv < 8; ++wv) m1 = fmaxf(m1, wm[wv][j1]);
    mseg[4 + r] = m1;
  }
  float d8[8];
#pragma unroll
  for (int r = 0; r < 8; ++r) d8[r] = 0.f;
#pragma unroll
  for (int i = 0; i < 5; ++i) {
    int ti = w + 8 * i;
    if (ti < ntl) {
      int n = (seg * 40 + ti) * 16 + lr;
      bool valid = n < NS;
#pragma unroll
      for (int r = 0; r < 4; ++r) {
        float p0 = __expf(s0[i][r] - mseg[r]);
        float p1 = __expf(s1[i][r] - mseg[4 + r]);
        if (valid) {
          P[((size_t)b * NJ + lg * 4 + r) * KP + n] = f2bf(p0);
          d8[r] += p0;
          if (lg < 2) {
            P[((size_t)b * NJ + 16 + lg * 4 + r) * KP + n] = f2bf(p1);
            d8[4 + r] += p1;
          }
        }
      }
    }
  }
#pragma unroll
  for (int r = 0; r < 8; ++r)
#pragma unroll
    for (int off = 1; off < 16; off <<= 1)
      d8[r] += __shfl_xor(d8[r], off);
  if (lr == 0) {
#pragma unroll
    for (int r = 0; r < 4; ++r) {
      wd[w][lg * 4 + r] = d8[r];
      if (lg < 2) wd[w][16 + lg * 4 + r] = d8[4 + r];
    }
  }
  __syncthreads();
  if (threadIdx.x < NJ) {
    int j = threadIdx.x;
    float m = wm[0][j], d = 0.f;
#pragma unroll
    for (int wv = 1; wv < 8; ++wv) m = fmaxf(m, wm[wv][j]);
#pragma unroll
    for (int wv = 0; wv < 8; ++wv) d += wd[wv][j];
    float* mp = md + ((size_t)b * QSEG + seg) * 48;
    mp[j] = m;
    mp[24 + j] = d;
  }
}

// combine md -> cs[4]; write attention f32 from RAW P; zero P's n-pad;
// store cs for kR4. P is NOT renormalized (factored into kR4).
__global__ __launch_bounds__(256) void kW(unsigned short* __restrict__ P,
                                          const float* __restrict__ md,
                                          float* __restrict__ attn,
                                          float* __restrict__ csb) {
  int bj = blockIdx.x;
  int b = bj / NJ, j = bj - b * NJ;
  const float* mp = md + (size_t)b * (QSEG * 48);
  float ms[QSEG];
  float m = -1e30f;
#pragma unroll
  for (int s = 0; s < QSEG; ++s) { ms[s] = mp[s * 48 + j]; m = fmaxf(m, ms[s]); }
  float d = 0.f;
#pragma unroll
  for (int s = 0; s < QSEG; ++s) d += mp[s * 48 + 24 + j] * __expf(ms[s] - m);
  float rinv = 1.f / d;
  float cs[QSEG];
#pragma unroll
  for (int s = 0; s < QSEG; ++s) cs[s] = __expf(ms[s] - m) * rinv;
  if (threadIdx.x < QSEG) {
    float v = cs[0];
    if (threadIdx.x == 1) v = cs[1];
    if (threadIdx.x == 2) v = cs[2];
    if (threadIdx.x == 3) v = cs[3];
    csb[(size_t)bj * QSEG + threadIdx.x] = v;
  }

  unsigned* prow = (unsigned*)(P + (size_t)bj * KP);
  float2* arow = (float2*)(attn + (size_t)bj * NS);
  for (int i = threadIdx.x; i < NS / 2; i += 256) {
    unsigned pk = prow[i];
    int n0 = 2 * i;
    float p0 = bf2f(pk & 0xffffu) * cs[n0 / TSEG];
    float p1 = bf2f(pk >> 16) * cs[(n0 + 1) / TSEG];
    arow[i] = make_float2(p0, p1);
  }
  if (threadIdx.x < (KP - NS) / 2) prow[NS / 2 + threadIdx.x] = 0;   // pad zeros
}

// =============== FP32 fallback (round-3, known-pass) ===============
#define KSEG 8
#define CSEG 313
#define SEGN 625
#define TN 64
#define LDP 132
#define WS_W1T 0u
#define WS_QTF 60000u
#define WS_MDF (WS_QTF + 804864u)
#define WS_PHF (WS_MDF + (unsigned)(NB * QSEG * 48))
#define SEGSTRIDE ((size_t)NB * NJ * DF)

__global__ __launch_bounds__(256) void kT_f(const float* __restrict__ W1,
                                            float* __restrict__ W1t) {
  int i = blockIdx.x * 256 + threadIdx.x;
  if (i >= NJ * NS) return;
  int o = i / NS, c = i - o * NS;
  W1t[c * NJ + o] = W1[i];
}

__global__ __launch_bounds__(192) void kH_f(const float* __restrict__ sf,
                                            const float* __restrict__ W1t,
                                            float* __restrict__ ph) {
  int b = blockIdx.x >> 3;
  int s = blockIdx.x & 7;
  int l = threadIdx.x;
  int c0 = s * CSEG;
  int cnt = NS - c0; if (cnt > CSEG) cnt = CSEG;
  const float* xp = sf + (size_t)b * (NS * DF) + (size_t)c0 * DF;
  const float* wp = W1t + (size_t)c0 * NJ;
  float acc[NJ];
#pragma unroll
  for (int o = 0; o < NJ; ++o) acc[o] = 0.f;
  if (l < DF) {
#pragma unroll 2
    for (int c = 0; c < cnt; ++c) {
      float xv = xp[(size_t)c * DF + l];
#pragma unroll
      for (int o = 0; o < NJ; ++o) acc[o] = fmaf(wp[c * NJ + o], xv, acc[o]);
    }
    float* pp = ph + (size_t)(s * NB + b) * (NJ * DF) + l;
#pragma unroll
    for (int o = 0; o < NJ; ++o) pp[o * DF] = acc[o];
  }
}

__global__ __launch_bounds__(512) void k1b_f(const float* __restrict__ ph,
                                             const float* __restrict__ W2,
                                             const float* __restrict__ b1v,
                                             const float* __restrict__ b2v,
                                             float* __restrict__ q_t) {
  int flat = blockIdx.x * 512 + threadIdx.x;
  if (flat >= NB * DF) return;
  int l = flat % DF;
  int b = flat / DF;
  const float* p0 = ph + (size_t)(b * NJ) * DF + l;
  float hv[NJ];
#pragma unroll
  for (int o = 0; o < NJ; ++o) hv[o] = b1v[o];
  for (int s = 0; s < KSEG; ++s) {
#pragma unroll
    for (int o = 0; o < NJ; ++o) hv[o] += p0[s * SEGSTRIDE + o * DF];
  }
#pragma unroll
  for (int o = 0; o < NJ; ++o) hv[o] = fmaxf(hv[o], 0.f);
  float q[NJ];
  for (int o = 0; o < NJ; ++o) {
    float sv = b2v[o];
#pragma unroll
    for (int i = 0; i < NJ; ++i) sv = fmaf(W2[o * NJ + i], hv[i], sv);
    q[o] = sv;
  }
  float4* qp = (float4*)(q_t + (size_t)flat * NJ);
#pragma unroll
  for (int v = 0; v < 6; ++v)
    qp[v] = make_float4(q[4 * v], q[4 * v + 1], q[4 * v + 2], q[4 * v + 3]);
}

__global__ __launch_bounds__(256) void k2_f(const float* __restrict__ sf,
                                            const float* __restrict__ q_t,
                                            float* __restrict__ raw,
                                            float* __restrict__ md) {
  __shared__ __align__(16) float xs[TN * LDP];
  int b = blockIdx.x >> 2;
  int s = blockIdx.x & 3;
  int tid = threadIdx.x;
  int wid = tid >> 6, lane = tid & 63;
  int jq = __builtin_amdgcn_readfirstlane(wid);

  const float* sft = sf + (size_t)b * (NS * DF) + (size_t)(s * SEGN) * DF;
  const float* qb = q_t + (size_t)b * (DF * NJ) + jq * 6;
  float* rawb = raw + (size_t)b * (NJ * NS) + (size_t)(s * SEGN);

  float m6[6], d6[6];
#pragma unroll
  for (int i = 0; i < 6; ++i) { m6[i] = -1e30f; d6[i] = 0.f; }

  const int NT = (SEGN + TN - 1) / TN;
  for (int t = 0; t < NT; ++t) {
    int n0 = t * TN;
    int nmax = SEGN - n0; if (nmax > TN) nmax = TN;
    __syncthreads();
#pragma unroll
    for (int rr = 0; rr < 16; ++rr) {
      int r = wid * 16 + rr;
      if (r < nmax) {
        const float* g = sft + (size_t)(n0 + r) * DF;
        float* d = xs + r * LDP;
        d[lane] = g[lane];
        d[64 + lane] = g[64 + lane];
        if (lane < 3) d[128 + lane] = g[128 + lane];
      }
    }
    __syncthreads();
    if (lane < nmax) {
      const float* xrow = xs + lane * LDP;
      float sa[6];
#pragma unroll
      for (int i = 0; i < 6; ++i) sa[i] = 0.f;
      for (int l4 = 0; l4 < 32; ++l4) {
        float4 xv = *(const float4*)(xrow + 4 * l4);
        const float* q4 = qb + (4 * l4) * NJ;
#pragma unroll
        for (int i = 0; i < 6; ++i) sa[i] = fmaf(q4[i], xv.x, sa[i]);
#pragma unroll
        for (int i = 0; i < 6; ++i) sa[i] = fmaf(q4[NJ + i], xv.y, sa[i]);
#pragma unroll
        for (int i = 0; i < 6; ++i) sa[i] = fmaf(q4[2 * NJ + i], xv.z, sa[i]);
#pragma unroll
        for (int i = 0; i < 6; ++i) sa[i] = fmaf(q4[3 * NJ + i], xv.w, sa[i]);
      }
#pragma unroll
      for (int l = 128; l < DF; ++l) {
        float xv = xrow[l];
#pragma unroll
        for (int i = 0; i < 6; ++i) sa[i] = fmaf(qb[l * NJ + i], xv, sa[i]);
      }
      int nr = n0 + lane;
#pragma unroll
      for (int i = 0; i < 6; ++i) {
        rawb[(size_t)(jq * 6 + i) * NS + nr] = sa[i];
        float mn = fmaxf(m6[i], sa[i]);
        d6[i] = d6[i] * __expf(m6[i] - mn) + __expf(sa[i] - mn);
        m6[i] = mn;
      }
    }
  }
#pragma unroll
  for (int i = 0; i < 6; ++i) {
    float m = m6[i], d = d6[i];
    for (int off = 32; off > 0; off >>= 1) {
      float mo = __shfl_xor(m, off);
      float dd = __shfl_xor(d, off);
      float nm = fmaxf(m, mo);
      d = d * __expf(m - nm) + dd * __expf(mo - nm);
      m = nm;
    }
    m6[i] = m; d6[i] = d;
  }
  if (lane == 0) {
    float* mp = md + ((size_t)b * QSEG + s) * 48;
#pragma unroll
    for (int i = 0; i < 6; ++i) {
      mp[jq * 6 + i] = m6[i];
      mp[24 + jq * 6 + i] = d6[i];
    }
  }
}

__global__ __launch_bounds__(256) void k3_f(float* __restrict__ attn,
                                            const float* __restrict__ md) {
  int bj = blockIdx.x;
  int b = bj / NJ;
  int j = bj - b * NJ;
  const float* mp = md + (size_t)b * (QSEG * 48);
  float m = -1e30f, d = 0.f;
#pragma unroll
  for (int s = 0; s < QSEG; ++s) {
    float ms = mp[s * 48 + j], ds = mp[s * 48 + 24 + j];
    float nm = fmaxf(m, ms);
    d = d * __expf(m - nm) + ds * __expf(ms - nm);
    m = nm;
  }
  float r = 1.f / d;
  float* p = attn + (size_t)bj * NS;
  for (int n = threadIdx.x; n < NS; n += 256)
    p[n] = __expf(p[n] - m) * r;
}

__global__ __launch_bounds__(192) void k4_f(const float* __restrict__ sf,
                                            const float* __restrict__ attn,
                                            float* __restrict__ po) {
  int b = blockIdx.x >> 3;
  int s = blockIdx.x & 7;
  int l = threadIdx.x;
  int n0 = s * CSEG;
  int cnt = NS - n0; if (cnt > CSEG) cnt = CSEG;
  const float* xp = sf + (size_t)b * (NS * DF) + (size_t)n0 * DF;
  const float* ap = attn + (size_t)b * (NJ * NS) + n0;
  float acc[NJ];
#pragma unroll
  for (int o = 0; o < NJ; ++o) acc[o] = 0.f;
  if (l < DF) {
#pragma unroll 2
    for (int n = 0; n < cnt; ++n) {
      float xv = xp[(size_t)n * DF + l];
#pragma unroll
      for (int o = 0; o < NJ; ++o) acc[o] = fmaf(ap[(size_t)o * NS + n], xv, acc[o]);
    }
    float* pp = po + (size_t)(s * NB + b) * (NJ * DF) + l;
#pragma unroll
    for (int o = 0; o < NJ; ++o) pp[o * DF] = acc[o];
  }
}

__global__ __launch_bounds__(512) void k5_f(const float* __restrict__ po,
                                            float* __restrict__ out) {
  int i = blockIdx.x * 512 + threadIdx.x;
  float v = 0.f;
#pragma unroll
  for (int s = 0; s < KSEG; ++s) v += po[s * SEGSTRIDE + i];
  out[i] = v;
}

extern "C" void kernel_launch(void* const* d_in, const int* in_sizes, int n_in,
                              void* d_out, int out_size, void* d_ws, size_t ws_size,
                              hipStream_t stream) {
  const float* sf = (const float*)d_in[0];
  const float* W1 = (const float*)d_in[1];
  const float* b1 = (const float*)d_in[2];
  const float* W2 = (const float*)d_in[3];
  const float* b2 = (const float*)d_in[4];
  float* out = (float*)d_out;
  float* attn = out + (size_t)NB * NJ * DF;

  if (ws_size >= WS_FULL) {
    unsigned short* Xn  = (unsigned short*)((char*)d_ws + F_XN);
    unsigned short* W1b = (unsigned short*)((char*)d_ws + F_W1B);
    unsigned short* qbf = (unsigned short*)((char*)d_ws + F_QBF);
    float* po   = (float*)((char*)d_ws + F_PO);
    float* md   = (float*)((char*)d_ws + F_MD);
    float* csb  = (float*)((char*)d_ws + F_CS);
    unsigned short* P   = (unsigned short*)((char*)d_ws + F_P);

    kT2<<<158, 256, 0, stream>>>(W1, W1b);
    kPn<<<NB * 20, 256, 0, stream>>>(sf, Xn);
    kMM<<<NB * 4, 512, 0, stream>>>(Xn, W1b, 0, 31, po);   // h partials
    k1b<<<68, 512, 0, stream>>>(po, W2, b1, b2, qbf);      // reduce + q
    k2m<<<NB * QSEG, 512, 0, stream>>>(Xn, qbf, P, md);
    kW <<<NB * NJ, 256, 0, stream>>>(P, md, attn, csb);
    kMM<<<NB * 4, 512, 0, stream>>>(Xn, P, NJ, 23, po);    // out partials (raw P)
    kR4<<<1572, 512, 0, stream>>>(po, csb, out);
  } else {
    float* ws = (float*)d_ws;
    float* W1t = ws + WS_W1T;
    float* q_t = ws + WS_QTF;
    float* md  = ws + WS_MDF;
    float* ph  = ws + WS_PHF;
    kT_f <<<235, 256, 0, stream>>>(W1, W1t);
    kH_f <<<NB * KSEG, 192, 0, stream>>>(sf, W1t, ph);
    k1b_f<<<66, 512, 0, stream>>>(ph, W2, b1, b2, q_t);
    k2_f <<<NB * QSEG, 256, 0, stream>>>(sf, q_t, attn, md);
    k3_f <<<NB * NJ, 256, 0, stream>>>(attn, md);
    k4_f <<<NB * KSEG, 192, 0, stream>>>(sf, attn, ph);
    k5_f <<<1572, 512, 0, stream>>>(ph, out);
  }
}